// Round 10
// baseline (276.089 us; speedup 1.0000x reference)
//
#include <hip/hip_runtime.h>
#include <math.h>
#include <stdint.h>

// B=8, S=2048, D=512 single-head self-attention, fp32 in/out, fp16 MFMA inside.
// Round 17 = mixed-core consolidation (r9 post-mortem: wall delta decomposes
// as scores+proj -3.7us on 32x32 core, av +7.4us on it):
//   - scores/proj: 32x32x16 core with 3-term XOR swizzle (r9, 0 conflicts).
//   - av: r4's 16x16x32 core (best av all session), WITH the in-loop rowsum
//     REMOVED: l[b][s] = rowsum(P) is now computed in scores' epilogue from
//     the same fp16-quantized P values (numerics-identical sum), reduced via
//     5x shfl_xor over the 32-lane group, atomicAdd'ed to a 64KB l array
//     (device-scope atomics = XCD-safe, m20). prep zeroes l each launch.
//   - av epilogue divides by l from global (L2-hot) -> av loop is pure GEMM.
// r9: 3-term swizzle verified (conflicts 4.19M -> 0).
// r8 lesson: 2-term swizzle breaks for 32x32 frag reads (rows 16 apart).
// r7 lesson: 128x64 tiles / 3 blocks/CU regressed (FETCH +18%).
// r6 lesson: 8-wave same-tile TLP regressed (LDS amplification).
// r5 lesson: grid.sync fusion = 345us (XCD L2 writeback per boundary).
//
//  1. prep:        Xh = fp16(x);  W*T = fp16(W^T) for q,k,v;  l = 0
//  2. proj_mfma:   z=0: Qh=(Xh.Wq+bq)/sqrt(512)  z=1: Kh=Xh.Wk+bk
//                  z=2: Vt[b][d][s] = (Xh.Wv + bv)^T  (transposed GEMM)
//  3. scores_mfma: P[b] = fp16(exp(Qh.Kh^T)) UNNORMALIZED; l[b] += rowsum(P)
//  4. av_mfma:     out[b] = (P.V) * mask[row] / l[row]

typedef _Float16 f16x8 __attribute__((ext_vector_type(8)));
typedef _Float16 f16x4 __attribute__((ext_vector_type(4)));
typedef float f32x4 __attribute__((ext_vector_type(4)));
typedef float f32x16 __attribute__((ext_vector_type(16)));

__device__ __forceinline__ void async16(const _Float16* g, _Float16* l) {
    __builtin_amdgcn_global_load_lds(
        (const __attribute__((address_space(1))) unsigned int*)(uintptr_t)g,
        (__attribute__((address_space(3))) unsigned int*)(unsigned int)(uintptr_t)l,
        16, 0, 0);
}

#define MFMA16(a, b, c) __builtin_amdgcn_mfma_f32_16x16x32_f16(a, b, c, 0, 0, 0)
#define MFMA32(a, b, c) __builtin_amdgcn_mfma_f32_32x32x16_f16(a, b, c, 0, 0, 0)
#define BAR() __builtin_amdgcn_s_barrier()
#define LGKM0() asm volatile("s_waitcnt lgkmcnt(0)" ::: "memory")

// ---------------------------------------------------------------------------
// core16 (r4-proven, RS removed): acc[4][4](16x16) += A[row0:+128][0:K] .
// B[col0:+128][0:K]^T, BK=64, 4 waves 2x2 (per-wave 64x64).
// LDS buffer 32KB: A chunks 0..15 @ c*1KB, B chunks 0..15 @ 8KB + c*1KB;
// chunk = 8 rows x 64 halves, one async16 (XOR-swizzled source, linear dest).
// Element [row][k] at buf[row*64 + ((k/8)^(row&7))*8 + k%8].
//  P0: read A(8)+Bearly(4); stage t+1's B-late -> other buf | MFMA n=0,1
//  P1: read Blate(4); stage t+2's A+Bearly -> this buf; vmcnt(6) | MFMA n=2,3
//  Ledger: tile t = {A,Bearly}@P1(t-2) + {Blate}@P0(t-1); vmcnt(6) after
//  P1(t)'s 6-chunk issue -> t+1 fully landed. Stage targets read-complete
//  one barrier earlier (race-free).
// ---------------------------------------------------------------------------
template <int NT>
__device__ __forceinline__ void core16(
    const _Float16* __restrict__ A, const _Float16* __restrict__ B,
    int ld, int row0, int col0, _Float16* sm, f32x4 acc[4][4])
{
    const int tid = threadIdx.x, lane = tid & 63, wave = tid >> 6;
    const int wm = wave >> 1, wn = wave & 1;
    const int rc = lane >> 3;
    const int swz = ((lane & 7) ^ rc) * 8;
    const int fr = lane & 15, q = lane >> 4, fx = fr & 7;
    const size_t laneoff = (size_t)rc * ld + swz;

    const _Float16* gA[4]; int lA[4];
#pragma unroll
    for (int i = 0; i < 4; i++) {
        int c = wave * 4 + i;                        // A chunks 0..15
        gA[i] = A + (size_t)(row0 + 8 * c) * ld + laneoff;
        lA[i] = c * 512;
    }
    const _Float16* gBe[2]; const _Float16* gBl[2]; int lBe[2], lBl[2];
#pragma unroll
    for (int i = 0; i < 2; i++) {
        int idx = wave * 2 + i;                      // 0..7
        int je = (idx & 3) + (idx >> 2) * 8;         // early {0-3,8-11}
        int jl = je + 4;                             // late  {4-7,12-15}
        gBe[i] = B + (size_t)(col0 + 8 * je) * ld + laneoff;
        gBl[i] = B + (size_t)(col0 + 8 * jl) * ld + laneoff;
        lBe[i] = 8192 + je * 512;
        lBl[i] = 8192 + jl * 512;
    }

    // prologue: tile0 full (8/wave), tile1 A+Bearly (6/wave); vmcnt(6)=t0 done
#pragma unroll
    for (int i = 0; i < 4; i++) async16(gA[i], sm + lA[i]);
#pragma unroll
    for (int i = 0; i < 2; i++) async16(gBe[i], sm + lBe[i]);
#pragma unroll
    for (int i = 0; i < 2; i++) async16(gBl[i], sm + lBl[i]);
#pragma unroll
    for (int i = 0; i < 4; i++) async16(gA[i] + 64, sm + 16384 + lA[i]);
#pragma unroll
    for (int i = 0; i < 2; i++) async16(gBe[i] + 64, sm + 16384 + lBe[i]);
    asm volatile("s_waitcnt vmcnt(6)" ::: "memory");
    BAR();

#pragma unroll 2
    for (int t = 0; t < NT; ++t) {
        const _Float16* As = sm + (t & 1) * 16384;
        const _Float16* Bs = As + 8192;
        f16x8 af[4][2], b0f[2][2], b1f[2][2];

        // ---- P0: read A + B-early; stage t+1's B-late into the other buffer
#pragma unroll
        for (int m = 0; m < 4; m++)
#pragma unroll
            for (int s = 0; s < 2; s++) {
                int ra = wm * 64 + m * 16 + fr;
                af[m][s] = *(const f16x8*)&As[ra * 64 + (((s * 4 + q) ^ fx) * 8)];
            }
#pragma unroll
        for (int n = 0; n < 2; n++)
#pragma unroll
            for (int s = 0; s < 2; s++) {
                int rb = wn * 64 + n * 16 + fr;
                b0f[n][s] = *(const f16x8*)&Bs[rb * 64 + (((s * 4 + q) ^ fx) * 8)];
            }
        if (t + 1 < NT) {
            _Float16* nb = sm + ((t + 1) & 1) * 16384;
#pragma unroll
            for (int i = 0; i < 2; i++)
                async16(gBl[i] + (t + 1) * 64, nb + lBl[i]);
        }
        BAR(); LGKM0();
        __builtin_amdgcn_s_setprio(1);
#pragma unroll
        for (int s = 0; s < 2; s++)
#pragma unroll
            for (int m = 0; m < 4; m++)
#pragma unroll
                for (int n = 0; n < 2; n++)
                    acc[m][n] = MFMA16(af[m][s], b0f[n][s], acc[m][n]);
        __builtin_amdgcn_s_setprio(0);
        BAR();

        // ---- P1: read B-late; stage t+2's A+B-early into this buffer
#pragma unroll
        for (int n = 0; n < 2; n++)
#pragma unroll
            for (int s = 0; s < 2; s++) {
                int rb = wn * 64 + (2 + n) * 16 + fr;
                b1f[n][s] = *(const f16x8*)&Bs[rb * 64 + (((s * 4 + q) ^ fx) * 8)];
            }
        if (t + 2 < NT) {
            _Float16* stg = sm + (t & 1) * 16384;
            const int k2 = (t + 2) * 64;
#pragma unroll
            for (int i = 0; i < 4; i++) async16(gA[i] + k2, stg + lA[i]);
#pragma unroll
            for (int i = 0; i < 2; i++) async16(gBe[i] + k2, stg + lBe[i]);
            asm volatile("s_waitcnt vmcnt(6)" ::: "memory");   // t+1 landed
        } else {
            asm volatile("s_waitcnt vmcnt(0)" ::: "memory");   // tail drain
        }
        BAR(); LGKM0();
        __builtin_amdgcn_s_setprio(1);
#pragma unroll
        for (int s = 0; s < 2; s++)
#pragma unroll
            for (int m = 0; m < 4; m++)
#pragma unroll
                for (int n = 0; n < 2; n++)
                    acc[m][2 + n] = MFMA16(af[m][s], b1f[n][s], acc[m][2 + n]);
        __builtin_amdgcn_s_setprio(0);
        BAR();
    }
}

// ---------------------------------------------------------------------------
// core32 (r9, 0 conflicts): acc[2][2](32x32) += A[row0:+128][0:K] .
// B[col0:+128][0:K]^T, BK=64, 4 waves 2x2. 3-term swizzle:
// element [row][k] at buf[row*64 + ((k/8)^(row&7)^((row>>3)&3))*8 + k%8].
// Frag reads: lane -> row (lane&31), k = s*16 + (lane>>5)*8.
// Same 2-phase schedule / vmcnt(6) ledger as core16.
// ---------------------------------------------------------------------------
template <int NT>
__device__ __forceinline__ void core32(
    const _Float16* __restrict__ A, const _Float16* __restrict__ B,
    int ld, int row0, int col0, _Float16* sm, f32x16 acc[2][2])
{
    const int tid = threadIdx.x, lane = tid & 63, wave = tid >> 6;
    const int wm = wave >> 1, wn = wave & 1;
    const int rc = lane >> 3;
    const int l7 = lane & 7;
    const int fr32 = lane & 31, q2 = lane >> 5;
    const int fx = fr32 & 7;
    const int rq = (lane >> 3) & 3;

    const _Float16* gA[4]; int lA[4];
#pragma unroll
    for (int i = 0; i < 4; i++) {
        int c = wave * 4 + i;
        int swz = ((l7 ^ rc ^ (c & 3)) * 8);
        gA[i] = A + (size_t)(row0 + 8 * c + rc) * ld + swz;
        lA[i] = c * 512;
    }
    const _Float16* gBe[2]; const _Float16* gBl[2]; int lBe[2], lBl[2];
#pragma unroll
    for (int i = 0; i < 2; i++) {
        int idx = wave * 2 + i;
        int je = (idx & 3) + (idx >> 2) * 8;
        int jl = je + 4;
        int swze = ((l7 ^ rc ^ (je & 3)) * 8);
        int swzl = ((l7 ^ rc ^ (jl & 3)) * 8);
        gBe[i] = B + (size_t)(col0 + 8 * je + rc) * ld + swze;
        gBl[i] = B + (size_t)(col0 + 8 * jl + rc) * ld + swzl;
        lBe[i] = 8192 + je * 512;
        lBl[i] = 8192 + jl * 512;
    }

#pragma unroll
    for (int i = 0; i < 4; i++) async16(gA[i], sm + lA[i]);
#pragma unroll
    for (int i = 0; i < 2; i++) async16(gBe[i], sm + lBe[i]);
#pragma unroll
    for (int i = 0; i < 2; i++) async16(gBl[i], sm + lBl[i]);
#pragma unroll
    for (int i = 0; i < 4; i++) async16(gA[i] + 64, sm + 16384 + lA[i]);
#pragma unroll
    for (int i = 0; i < 2; i++) async16(gBe[i] + 64, sm + 16384 + lBe[i]);
    asm volatile("s_waitcnt vmcnt(6)" ::: "memory");
    BAR();

#pragma unroll 2
    for (int t = 0; t < NT; ++t) {
        const _Float16* As = sm + (t & 1) * 16384;
        const _Float16* Bs = As + 8192;
        f16x8 af[2][4], bf[4];

        // ---- P0: read A(all) + B nf=0; stage t+1's B-late
#pragma unroll
        for (int m = 0; m < 2; m++)
#pragma unroll
            for (int s = 0; s < 4; s++) {
                int ra = wm * 64 + m * 32 + fr32;
                af[m][s] = *(const f16x8*)&As[ra * 64 + ((((2 * s + q2) ^ fx ^ rq)) * 8)];
            }
#pragma unroll
        for (int s = 0; s < 4; s++) {
            int rb = wn * 64 + fr32;
            bf[s] = *(const f16x8*)&Bs[rb * 64 + ((((2 * s + q2) ^ fx ^ rq)) * 8)];
        }
        if (t + 1 < NT) {
            _Float16* nb = sm + ((t + 1) & 1) * 16384;
#pragma unroll
            for (int i = 0; i < 2; i++)
                async16(gBl[i] + (t + 1) * 64, nb + lBl[i]);
        }
        BAR(); LGKM0();
        __builtin_amdgcn_s_setprio(1);
#pragma unroll
        for (int s = 0; s < 4; s++)
#pragma unroll
            for (int m = 0; m < 2; m++)
                acc[m][0] = MFMA32(af[m][s], bf[s], acc[m][0]);
        __builtin_amdgcn_s_setprio(0);
        BAR();

        // ---- P1: read B nf=1; stage t+2's A+B-early
#pragma unroll
        for (int s = 0; s < 4; s++) {
            int rb = wn * 64 + 32 + fr32;
            bf[s] = *(const f16x8*)&Bs[rb * 64 + ((((2 * s + q2) ^ fx ^ rq)) * 8)];
        }
        if (t + 2 < NT) {
            _Float16* stg = sm + (t & 1) * 16384;
            const int k2 = (t + 2) * 64;
#pragma unroll
            for (int i = 0; i < 4; i++) async16(gA[i] + k2, stg + lA[i]);
#pragma unroll
            for (int i = 0; i < 2; i++) async16(gBe[i] + k2, stg + lBe[i]);
            asm volatile("s_waitcnt vmcnt(6)" ::: "memory");
        } else {
            asm volatile("s_waitcnt vmcnt(0)" ::: "memory");
        }
        BAR(); LGKM0();
        __builtin_amdgcn_s_setprio(1);
#pragma unroll
        for (int s = 0; s < 4; s++)
#pragma unroll
            for (int m = 0; m < 2; m++)
                acc[m][1] = MFMA32(af[m][s], bf[s], acc[m][1]);
        __builtin_amdgcn_s_setprio(0);
        BAR();
    }
}

// ---------------- 1. prep: x->fp16, W->fp16 W^T, zero l ---------------------
__global__ __launch_bounds__(256) void prep(
    const float* __restrict__ x,
    const float* __restrict__ Wq, const float* __restrict__ Wk,
    const float* __restrict__ Wv,
    _Float16* __restrict__ Xh,
    _Float16* __restrict__ WqT, _Float16* __restrict__ WkT,
    _Float16* __restrict__ WvT, float* __restrict__ lsum)
{
    const int bid = blockIdx.x;
    if (bid < 8192) {                       // convert x: 8.4M elems / 1024
        int i = (bid * 256 + threadIdx.x) * 4;
        float4 v = *(const float4*)(x + i);
        f16x4 h;
        h.x = (_Float16)v.x; h.y = (_Float16)v.y;
        h.z = (_Float16)v.z; h.w = (_Float16)v.w;
        *(f16x4*)&Xh[i] = h;
    } else if (bid < 11264) {               // transpose W: 3 x 1024 blocks
        int t = bid - 8192;
        int z = t >> 10;
        const float* W = (z == 0) ? Wq : (z == 1) ? Wk : Wv;
        _Float16* Wt   = (z == 0) ? WqT : (z == 1) ? WkT : WvT;
        int idx = (t & 1023) * 256 + threadIdx.x;
        int n = idx >> 9, k = idx & 511;
        Wt[idx] = (_Float16)W[k * 512 + n];
    } else {                                // zero l: 16384 f32 / 16 blocks
        int i = ((bid - 11264) * 256 + threadIdx.x) * 4;
        *(float4*)(lsum + i) = (float4){0.f, 0.f, 0.f, 0.f};
    }
}

// ---------------- 2. projections (core32) -----------------------------------
// grid (x=128, y=4, z=3), 256 thr. z<2: row0=bx*128 (X rows), col0=by*128.
// z=2: row0=by*128 (d), col0=bx*128 (s_global). 4 col-blocks of one row-tile
// have bids differing by 128 (=0 mod 8) -> same XCD -> X rows fetched once.
__global__ __launch_bounds__(256, 2) void proj_mfma(
    const _Float16* __restrict__ Xh,
    const _Float16* __restrict__ WqT, const float* __restrict__ bq,
    const _Float16* __restrict__ WkT, const float* __restrict__ bk,
    const _Float16* __restrict__ WvT, const float* __restrict__ bv,
    _Float16* __restrict__ Qh, _Float16* __restrict__ Kh,
    _Float16* __restrict__ Vt)
{
    __shared__ __align__(16) _Float16 smem[2 * 16384];
    const int z = blockIdx.z;
    f32x16 acc[2][2] = {};

    const int lane = threadIdx.x & 63, wave = threadIdx.x >> 6;
    const int wm = wave >> 1, wn = wave & 1;
    const int fr32 = lane & 31, q2 = lane >> 5;

    if (z < 2) {
        const _Float16* Wt = (z == 0) ? WqT : WkT;
        const float* bias  = (z == 0) ? bq : bk;
        _Float16* P        = (z == 0) ? Qh : Kh;
        const float sc     = (z == 0) ? 0.04419417382415922f : 1.0f;
        const int row0 = blockIdx.x * 128, col0 = blockIdx.y * 128;
        core32<8>(Xh, Wt, 512, row0, col0, smem, acc);
#pragma unroll
        for (int mf = 0; mf < 2; mf++)
#pragma unroll
            for (int nf = 0; nf < 2; nf++) {
                int col = col0 + wn * 64 + nf * 32 + fr32;
                float bb = bias[col];
#pragma unroll
                for (int reg = 0; reg < 16; reg++) {
                    int row = row0 + wm * 64 + mf * 32 +
                              (reg & 3) + 8 * (reg >> 2) + 4 * q2;
                    P[(size_t)row * 512 + col] = (_Float16)((acc[mf][nf][reg] + bb) * sc);
                }
            }
    } else {
        // transposed V: out(row=d, col=s_global) = sum_k WvT[d][k] * Xh[s][k]
        const int row0 = blockIdx.y * 128;   // d (M=512)
        const int col0 = blockIdx.x * 128;   // s_global (N=16384)
        core32<8>(WvT, Xh, 512, row0, col0, smem, acc);
#pragma unroll
        for (int mf = 0; mf < 2; mf++)
#pragma unroll
            for (int nf = 0; nf < 2; nf++) {
                int col = col0 + wn * 64 + nf * 32 + fr32;   // s_global
                size_t obase = (size_t)(col >> 11) * (512 * 2048) + (col & 2047);
#pragma unroll
                for (int reg = 0; reg < 16; reg++) {
                    int row = row0 + wm * 64 + mf * 32 +
                              (reg & 3) + 8 * (reg >> 2) + 4 * q2;  // d
                    Vt[obase + (size_t)row * 2048] = (_Float16)(acc[mf][nf][reg] + bv[row]);
                }
            }
    }
}

// ---------------- 3. scores: P = exp(Q.K^T), l += rowsum(P) -----------------
// grid 2048: batch = bid&7 (XCD pin: Q[b]+K[b]=4MB=one XCD L2), col fastest.
// Epilogue sums the fp16-quantized P per row (same values av's old fdot2
// summed), reduces over the 32-lane group, atomicAdds into l[b][row].
__global__ __launch_bounds__(256, 2) void scores_mfma(
    const _Float16* __restrict__ Qh, const _Float16* __restrict__ Kh,
    _Float16* __restrict__ Sh, float* __restrict__ lsum)
{
    __shared__ __align__(16) _Float16 smem[2 * 16384];
    const int bid = blockIdx.x;
    const int b   = bid & 7;
    const int rem = bid >> 3;
    const int col0 = (rem & 15) * 128;
    const int row0 = (rem >> 4) * 128;

    const _Float16* A = Qh + (size_t)b * 2048 * 512;
    const _Float16* B = Kh + (size_t)b * 2048 * 512;
    _Float16* S = Sh + (size_t)b * 2048 * 2048;
    float* lb = lsum + (size_t)b * 2048;

    f32x16 acc[2][2] = {};

    core32<8>(A, B, 512, row0, col0, smem, acc);

    const int lane = threadIdx.x & 63, wave = threadIdx.x >> 6;
    const int wm = wave >> 1, wn = wave & 1;
    const int fr32 = lane & 31, q2 = lane >> 5;

    float rsum[2][16];
#pragma unroll
    for (int mf = 0; mf < 2; mf++)
#pragma unroll
        for (int reg = 0; reg < 16; reg++) rsum[mf][reg] = 0.f;

#pragma unroll
    for (int mf = 0; mf < 2; mf++)
#pragma unroll
        for (int nf = 0; nf < 2; nf++) {
            int col = col0 + wn * 64 + nf * 32 + fr32;
#pragma unroll
            for (int reg = 0; reg < 16; reg++) {
                int row = row0 + wm * 64 + mf * 32 +
                          (reg & 3) + 8 * (reg >> 2) + 4 * q2;
                _Float16 h = (_Float16)__expf(acc[mf][nf][reg]);
                S[(size_t)row * 2048 + col] = h;
                rsum[mf][reg] += (float)h;
            }
        }
    // reduce over the 32 lanes of this q2 group (rows identical within group)
#pragma unroll
    for (int mf = 0; mf < 2; mf++)
#pragma unroll
        for (int reg = 0; reg < 16; reg++) {
            float v = rsum[mf][reg];
            v += __shfl_xor(v, 1, 64);
            v += __shfl_xor(v, 2, 64);
            v += __shfl_xor(v, 4, 64);
            v += __shfl_xor(v, 8, 64);
            v += __shfl_xor(v, 16, 64);
            rsum[mf][reg] = v;
        }
    if (fr32 == 0) {
#pragma unroll
        for (int mf = 0; mf < 2; mf++)
#pragma unroll
            for (int reg = 0; reg < 16; reg++) {
                int row = row0 + wm * 64 + mf * 32 +
                          (reg & 3) + 8 * (reg >> 2) + 4 * q2;
                atomicAdd(&lb[row], rsum[mf][reg]);
            }
    }
}

// ---------------- 4. out = (P.V) * mask / l ---------------------------------
// grid 512: batch = bid&7 (XCD pin: P[b] streams through one XCD L2,
// V[b]=2MB resident), col fastest. Pure GEMM loop (core16, no rowsum).
__global__ __launch_bounds__(256, 2) void av_mfma(
    const _Float16* __restrict__ Sh, const _Float16* __restrict__ Vt,
    const float* __restrict__ mask, const float* __restrict__ lsum,
    float* __restrict__ out)
{
    __shared__ __align__(16) _Float16 smem[2 * 16384];
    const int bid = blockIdx.x;
    const int b   = bid & 7;
    const int rem = bid >> 3;
    const int col0 = (rem & 3) * 128;
    const int row0 = (rem >> 2) * 128;

    const _Float16* A = Sh + (size_t)b * 2048 * 2048;
    const _Float16* B = Vt + (size_t)b * 512 * 2048;
    float* O = out + (size_t)b * 2048 * 512;
    const float* mk = mask + (size_t)b * 2048;
    const float* lb = lsum + (size_t)b * 2048;

    f32x4 acc[4][4];
#pragma unroll
    for (int i = 0; i < 4; i++)
#pragma unroll
        for (int j = 0; j < 4; j++) acc[i][j] = (f32x4){0.f, 0.f, 0.f, 0.f};

    core16<32>(A, B, 2048, row0, col0, smem, acc);

    const int lane = threadIdx.x & 63, wave = threadIdx.x >> 6;
    const int wm = wave >> 1, wn = wave & 1;
    const int er = (lane >> 4) * 4, ec = lane & 15;

#pragma unroll
    for (int tm = 0; tm < 4; tm++)
#pragma unroll
        for (int r = 0; r < 4; r++) {
            int row = row0 + wm * 64 + tm * 16 + er + r;
            float s = mk[row] / lb[row];
#pragma unroll
            for (int tn = 0; tn < 4; tn++) {
                int col = col0 + wn * 64 + tn * 16 + ec;
                O[(size_t)row * 512 + col] = acc[tm][tn][r] * s;
            }
        }
}

extern "C" void kernel_launch(void* const* d_in, const int* in_sizes, int n_in,
                              void* d_out, int out_size, void* d_ws, size_t ws_size,
                              hipStream_t stream) {
    const float* x    = (const float*)d_in[0];
    const float* mask = (const float*)d_in[1];
    const float* Wq   = (const float*)d_in[2];
    const float* bq   = (const float*)d_in[3];
    const float* Wk   = (const float*)d_in[4];
    const float* bk   = (const float*)d_in[5];
    const float* Wv   = (const float*)d_in[6];
    const float* bv   = (const float*)d_in[7];
    float* out = (float*)d_out;

    const size_t BSD = (size_t)8 * 2048 * 512;       // 8.4M halves
    const size_t SSZ = (size_t)8 * 2048 * 2048;      // 33.5M halves
    _Float16* base = (_Float16*)d_ws;
    _Float16* Qh  = base;
    _Float16* Kh  = Qh + BSD;
    _Float16* Vt  = Kh + BSD;                         // [b][d][s]
    _Float16* WqT = Vt + BSD;
    _Float16* WkT = WqT + 512 * 512;
    _Float16* WvT = WkT + 512 * 512;
    _Float16* Xh  = WvT + 512 * 512;
    _Float16* Sh  = Xh;                               // Xh dead after proj
    float*    lsum = (float*)(Sh + SSZ);              // 16384 f32 (64KB)

    prep<<<dim3(8192 + 3 * 1024 + 16), dim3(256), 0, stream>>>(
        x, Wq, Wk, Wv, Xh, WqT, WkT, WvT, lsum);
    proj_mfma<<<dim3(128, 4, 3), dim3(256), 0, stream>>>(
        Xh, WqT, bq, WkT, bk, WvT, bv, Qh, Kh, Vt);
    scores_mfma<<<dim3(2048), dim3(256), 0, stream>>>(Qh, Kh, Sh, lsum);
    av_mfma<<<dim3(512), dim3(256), 0, stream>>>(Sh, Vt, mask, lsum, out);
}